// Round 1
// baseline (38.234 us; speedup 1.0000x reference)
//
#include <hip/hip_runtime.h>
#include <hip/hip_bf16.h>

#define CORR_STRENGTH 0.1f
#define ERR_THRESH2 1e-12f   // (1e-6)^2 : norm(s) > 1e-6  <=>  |s|^2 > 1e-12

__global__ void __launch_bounds__(256) qec_kernel(
    const float* __restrict__ params,
    const float* __restrict__ Wsyn,   // [3][3]
    const float* __restrict__ bsyn,   // [3]
    const float* __restrict__ Wcorr,  // [3][3][3]
    const float* __restrict__ bcorr,  // [3][3]
    float* __restrict__ out,
    long long nvec,                   // number of 12-float (4-block) chunks
    long long nblk)                   // total number of 3-float blocks
{
    // Load tiny weights once per thread; uniform addresses -> cached broadcast.
    float ws[9], bs[3], wc[27], bc[9];
#pragma unroll
    for (int i = 0; i < 9; ++i)  ws[i] = Wsyn[i];
#pragma unroll
    for (int i = 0; i < 3; ++i)  bs[i] = bsyn[i];
#pragma unroll
    for (int i = 0; i < 27; ++i) wc[i] = Wcorr[i];
#pragma unroll
    for (int i = 0; i < 9; ++i)  bc[i] = bcorr[i];

    const long long tid     = (long long)blockIdx.x * blockDim.x + threadIdx.x;
    const long long nthread = (long long)gridDim.x * blockDim.x;

    // Main path: 4 blocks (12 floats) per iteration via 3x float4.
    const float4* __restrict__ src4 = reinterpret_cast<const float4*>(params);
    float4* __restrict__       dst4 = reinterpret_cast<float4*>(out);

    for (long long idx = tid; idx < nvec; idx += nthread) {
        float4 a = src4[idx * 3 + 0];
        float4 b = src4[idx * 3 + 1];
        float4 c = src4[idx * 3 + 2];

        float x[12] = { a.x, a.y, a.z, a.w,
                        b.x, b.y, b.z, b.w,
                        c.x, c.y, c.z, c.w };
        float y[12];

#pragma unroll
        for (int bl = 0; bl < 4; ++bl) {
            const float x0 = x[bl * 3 + 0];
            const float x1 = x[bl * 3 + 1];
            const float x2 = x[bl * 3 + 2];

            // syndromes: s[k] = Wsyn[k][:] . x + bsyn[k]
            float s[3];
#pragma unroll
            for (int k = 0; k < 3; ++k)
                s[k] = fmaf(ws[k * 3 + 0], x0,
                        fmaf(ws[k * 3 + 1], x1,
                         fmaf(ws[k * 3 + 2], x2, bs[k])));

            const float mag2 = s[0] * s[0] + s[1] * s[1] + s[2] * s[2];
            const bool active = mag2 > ERR_THRESH2;

            // correction[k] = sum_j s[j] * (Wcorr[j][k][:] . x + bcorr[j][k])
            float corr[3] = {0.f, 0.f, 0.f};
#pragma unroll
            for (int j = 0; j < 3; ++j) {
#pragma unroll
                for (int k = 0; k < 3; ++k) {
                    const float co = fmaf(wc[j * 9 + k * 3 + 0], x0,
                                      fmaf(wc[j * 9 + k * 3 + 1], x1,
                                       fmaf(wc[j * 9 + k * 3 + 2], x2, bc[j * 3 + k])));
                    corr[k] = fmaf(s[j], co, corr[k]);
                }
            }

#pragma unroll
            for (int k = 0; k < 3; ++k) {
                const float xv = x[bl * 3 + k];
                y[bl * 3 + k] = active ? (xv - CORR_STRENGTH * corr[k]) : xv;
            }
        }

        dst4[idx * 3 + 0] = make_float4(y[0], y[1], y[2],  y[3]);
        dst4[idx * 3 + 1] = make_float4(y[4], y[5], y[6],  y[7]);
        dst4[idx * 3 + 2] = make_float4(y[8], y[9], y[10], y[11]);
    }

    // Tail: any leftover 3-float blocks beyond nvec*4 (scalar path).
    const long long firstTailBlk = nvec * 4;
    for (long long blk = firstTailBlk + tid; blk < nblk; blk += nthread) {
        const float x0 = params[blk * 3 + 0];
        const float x1 = params[blk * 3 + 1];
        const float x2 = params[blk * 3 + 2];

        float s[3];
#pragma unroll
        for (int k = 0; k < 3; ++k)
            s[k] = fmaf(ws[k * 3 + 0], x0,
                    fmaf(ws[k * 3 + 1], x1,
                     fmaf(ws[k * 3 + 2], x2, bs[k])));

        const float mag2 = s[0] * s[0] + s[1] * s[1] + s[2] * s[2];
        const bool active = mag2 > ERR_THRESH2;

        float corr[3] = {0.f, 0.f, 0.f};
#pragma unroll
        for (int j = 0; j < 3; ++j) {
#pragma unroll
            for (int k = 0; k < 3; ++k) {
                const float co = fmaf(wc[j * 9 + k * 3 + 0], x0,
                                  fmaf(wc[j * 9 + k * 3 + 1], x1,
                                   fmaf(wc[j * 9 + k * 3 + 2], x2, bc[j * 3 + k])));
                corr[k] = fmaf(s[j], co, corr[k]);
            }
        }

        out[blk * 3 + 0] = active ? (x0 - CORR_STRENGTH * corr[0]) : x0;
        out[blk * 3 + 1] = active ? (x1 - CORR_STRENGTH * corr[1]) : x1;
        out[blk * 3 + 2] = active ? (x2 - CORR_STRENGTH * corr[2]) : x2;
    }
}

extern "C" void kernel_launch(void* const* d_in, const int* in_sizes, int n_in,
                              void* d_out, int out_size, void* d_ws, size_t ws_size,
                              hipStream_t stream) {
    const float* params = (const float*)d_in[0];
    const float* Wsyn   = (const float*)d_in[1];
    const float* bsyn   = (const float*)d_in[2];
    const float* Wcorr  = (const float*)d_in[3];
    const float* bcorr  = (const float*)d_in[4];
    float* out = (float*)d_out;

    const long long n    = (long long)in_sizes[0];  // total elements (divisible by 3 here)
    const long long nblk = n / 3;                   // 3-float blocks
    const long long nvec = n / 12;                  // 12-float (4-block) vector chunks

    const int block = 256;
    const int grid  = 2048;  // 256 CUs x 8 blocks; grid-stride covers the rest

    qec_kernel<<<grid, block, 0, stream>>>(params, Wsyn, bsyn, Wcorr, bcorr,
                                           out, nvec, nblk);
}